// Round 1
// baseline (1184.288 us; speedup 1.0000x reference)
//
#include <hip/hip_runtime.h>
#include <math.h>

#define BN 2
#define HH 160
#define WW 160
#define CDATA 8
#define CFEAT 8
#define CEMB 8
#define PS 10
#define STR 5
#define N1 31
#define N2 31
#define NSITE (N1*N2)
#define SWIN 15
#define NOFF 225
#define KK 7
#define EDIM 800   // CEMB*PS*PS = CDATA*PS*PS

// ---------- block reductions (256 threads = 4 waves) ----------
__device__ __forceinline__ float block_sum(float v, float* sred) {
    #pragma unroll
    for (int o = 32; o; o >>= 1) v += __shfl_xor(v, o);
    __syncthreads();                       // protect sred reuse
    if ((threadIdx.x & 63) == 0) sred[threadIdx.x >> 6] = v;
    __syncthreads();
    return sred[0] + sred[1] + sred[2] + sred[3];
}

__device__ __forceinline__ float block_max(float v, float* sred) {
    #pragma unroll
    for (int o = 32; o; o >>= 1) v = fmaxf(v, __shfl_xor(v, o));
    __syncthreads();
    if ((threadIdx.x & 63) == 0) sred[threadIdx.x >> 6] = v;
    __syncthreads();
    return fmaxf(fmaxf(sred[0], sred[1]), fmaxf(sred[2], sred[3]));
}

// ---------- 3x3 SAME conv, NCHW / OIHW, stride 1 ----------
// thread = 1 output pixel x NCO output channels. Weights are block-uniform -> s_loads.
template<int CIN, int NCO, bool RELU>
__global__ __launch_bounds__(256) void conv3x3_k(const float* __restrict__ in,
                                                 const float* __restrict__ wgt,
                                                 const float* __restrict__ bias,
                                                 float* __restrict__ out, int ngroups) {
    int x = blockIdx.x * 16 + threadIdx.x;
    int y = blockIdx.y * 16 + threadIdx.y;
    int bz = blockIdx.z;
    int b = bz / ngroups, g = bz % ngroups;
    int co0 = g * NCO;
    float acc[NCO];
    #pragma unroll
    for (int u = 0; u < NCO; u++) acc[u] = bias[co0 + u];
    const float* inb = in + (size_t)b * CIN * HH * WW;
    for (int c = 0; c < CIN; c++) {
        const float* inc = inb + (size_t)c * HH * WW;
        #pragma unroll
        for (int dy = 0; dy < 3; dy++) {
            int yy = y + dy - 1;
            bool yok = (yy >= 0 && yy < HH);
            #pragma unroll
            for (int dx = 0; dx < 3; dx++) {
                int xx = x + dx - 1;
                float v = (yok && xx >= 0 && xx < WW) ? inc[yy * WW + xx] : 0.f;
                #pragma unroll
                for (int u = 0; u < NCO; u++)
                    acc[u] = fmaf(v, wgt[((co0 + u) * CIN + c) * 9 + dy * 3 + dx], acc[u]);
            }
        }
    }
    float* outb = out + ((size_t)(b * (ngroups * NCO) + co0)) * HH * WW + y * WW + x;
    #pragma unroll
    for (int u = 0; u < NCO; u++) {
        float v = acc[u];
        if (RELU) v = fmaxf(v, 0.f);
        outb[(size_t)u * HH * WW] = v;
    }
}

// ---------- im2patch of xe -> ye rows, yn = ||ye||^2, tempv = exp(mean(log_temp patch)) ----------
__global__ __launch_bounds__(256) void im2patch_k(const float* __restrict__ xe,
                                                  const float* __restrict__ ltm,
                                                  float* __restrict__ ye,
                                                  float* __restrict__ yn,
                                                  float* __restrict__ tempv) {
    __shared__ float sred[4];
    int site = blockIdx.x;
    int b = site / NSITE; int ij = site % NSITE;
    int i1 = ij / N2, i2 = ij % N2;
    int t = threadIdx.x;
    const float* xeb = xe + (size_t)b * CEMB * HH * WW;
    float* yrow = ye + (size_t)site * EDIM;
    float ssq = 0.f;
    for (int e = t; e < EDIM; e += 256) {
        int c = e / 100; int rr = (e / 10) % 10; int q = e % 10;
        float v = xeb[(size_t)c * HH * WW + (i1 * STR + rr) * WW + (i2 * STR + q)];
        yrow[e] = v; ssq += v * v;
    }
    float tot = block_sum(ssq, sred);
    if (t == 0) yn[site] = tot;
    float sl = 0.f;
    if (t < 100) {
        int rr = t / 10, q = t % 10;
        sl = ltm[(size_t)b * HH * WW + (i1 * STR + rr) * WW + (i2 * STR + q)];
    }
    float slt = block_sum(sl, sred);
    if (t == 0) tempv[site] = expf(slt * (1.f / 100.f));
}

// ---------- distances to 225 window neighbors + K=7 iterated softmax -> Wk ----------
__global__ __launch_bounds__(256) void dist_softmax_k(const float* __restrict__ ye,
                                                      const float* __restrict__ yn,
                                                      const float* __restrict__ tempv,
                                                      float* __restrict__ wkout) {
    __shared__ float s_self[EDIM];
    __shared__ float s_win[NOFF][33];   // +1 pad: bank = (off+e)%32, conflict-free
    __shared__ float sred[4];
    int site = blockIdx.x;
    int b = site / NSITE; int ij = site % NSITE;
    int i1 = ij / N2, i2 = ij % N2;
    int t = threadIdx.x;
    const float* yself = ye + (size_t)site * EDIM;
    for (int e = t; e < EDIM; e += 256) s_self[e] = yself[e];
    int b1 = min(max(i1 - 7, 0), 16);
    int b2 = min(max(i2 - 7, 0), 16);
    __syncthreads();
    float dot = 0.f;
    for (int ec = 0; ec < EDIM; ec += 32) {
        for (int l = t; l < NOFF * 32; l += 256) {
            int so = l >> 5, e = l & 31;
            int nb = (b * N1 + (b1 + so / SWIN)) * N2 + (b2 + so % SWIN);
            s_win[so][e] = ye[(size_t)nb * EDIM + ec + e];
        }
        __syncthreads();
        if (t < NOFF) {
            #pragma unroll
            for (int e = 0; e < 32; e++) dot = fmaf(s_win[t][e], s_self[ec + e], dot);
        }
        __syncthreads();
    }
    float logit = -1e9f;
    if (t < NOFF) {
        int j1 = b1 + t / SWIN, j2 = b2 + t % SWIN;
        float xn = yn[(b * N1 + j1) * N2 + j2];
        float d = yn[site] + xn - 2.f * dot;
        logit = -d / tempv[site];
        if (j1 == i1 && j2 == i2) logit = -1e9f;   // self mask
    }
    float* wkr = wkout + (size_t)site * (KK * NOFF);
    for (int k = 0; k < KK; k++) {
        float m = block_max(logit, sred);
        float ex = expf(logit - m);          // -1e9 path underflows to exactly 0
        float s = block_sum(ex, sred);
        float wgt = ex / s;
        if (t < NOFF) wkr[k * NOFF + t] = wgt;
        logit += log1pf(-fminf(wgt, 1.f - 1e-6f));
    }
}

// ---------- aggregation + overlap-add fold (4-color launches -> no atomics) ----------
__global__ __launch_bounds__(256) void agg_k(const float* __restrict__ wk,
                                             const float* __restrict__ xd,
                                             float* __restrict__ acc,
                                             int c1, int c2, int n1c, int n2c) {
    __shared__ float swk[KK * NOFF];
    int t = threadIdx.x;
    int blk = blockIdx.x;
    int b = blk / (n1c * n2c); int r = blk % (n1c * n2c);
    int i1 = c1 + 2 * (r / n2c), i2 = c2 + 2 * (r % n2c);
    int site = (b * N1 + i1) * N2 + i2;
    const float* wkr = wk + (size_t)site * (KK * NOFF);
    for (int l = t; l < KK * NOFF; l += 256) swk[l] = wkr[l];
    __syncthreads();
    if (t >= 200) return;                  // 200 threads x 4 elems = 800
    int b1 = min(max(i1 - 7, 0), 16);
    int b2 = min(max(i2 - 7, 0), 16);
    int e0 = t * 4;
    int cd[4], pi[4], pj[4];
    #pragma unroll
    for (int u = 0; u < 4; u++) { int e = e0 + u; cd[u] = e / 100; pi[u] = (e / 10) % 10; pj[u] = e % 10; }
    float a[4][KK];
    #pragma unroll
    for (int u = 0; u < 4; u++)
        #pragma unroll
        for (int k = 0; k < KK; k++) a[u][k] = 0.f;
    for (int off = 0; off < NOFF; off++) {
        int j1 = b1 + off / SWIN, j2 = b2 + off % SWIN;
        float w0 = swk[0 * NOFF + off], w1 = swk[1 * NOFF + off], w2 = swk[2 * NOFF + off],
              w3 = swk[3 * NOFF + off], w4 = swk[4 * NOFF + off], w5 = swk[5 * NOFF + off],
              w6 = swk[6 * NOFF + off];
        #pragma unroll
        for (int u = 0; u < 4; u++) {
            float v = xd[((size_t)(b * CDATA + cd[u]) * HH + (j1 * STR + pi[u])) * WW + (j2 * STR + pj[u])];
            a[u][0] = fmaf(w0, v, a[u][0]); a[u][1] = fmaf(w1, v, a[u][1]);
            a[u][2] = fmaf(w2, v, a[u][2]); a[u][3] = fmaf(w3, v, a[u][3]);
            a[u][4] = fmaf(w4, v, a[u][4]); a[u][5] = fmaf(w5, v, a[u][5]);
            a[u][6] = fmaf(w6, v, a[u][6]);
        }
    }
    #pragma unroll
    for (int u = 0; u < 4; u++) {
        int h = i1 * STR + pi[u], w_ = i2 * STR + pj[u];
        #pragma unroll
        for (int k = 0; k < KK; k++) {
            int ch = (k + 1) * CDATA + cd[u];
            size_t idx = ((size_t)(b * 64 + ch) * HH + h) * WW + w_;
            acc[idx] += a[u][k];           // safe: same-color blocks never overlap
        }
    }
}

// ---------- finalize: out = [x_data ; acc/cnt - x_data] ----------
__global__ __launch_bounds__(256) void finalize_k(const float* __restrict__ acc,
                                                  const float* __restrict__ xd,
                                                  float* __restrict__ out) {
    int idx = blockIdx.x * 256 + threadIdx.x;
    if (idx >= BN * 64 * HH * WW) return;
    int w_ = idx % WW; int h = (idx / WW) % HH;
    int ch = (idx / (HH * WW)) % 64; int b = idx / (64 * HH * WW);
    int cd = ch & 7; int kk = ch >> 3;
    float xv = xd[((size_t)(b * CDATA + cd) * HH + h) * WW + w_];
    float o;
    if (kk == 0) {
        o = xv;
    } else {
        int lo1 = max(0, (h - 5) / 5),  hi1 = min(30, h / 5);
        int lo2 = max(0, (w_ - 5) / 5), hi2 = min(30, w_ / 5);
        float cnt = (float)((hi1 - lo1 + 1) * (hi2 - lo2 + 1));
        o = acc[idx] / cnt - xv;
    }
    out[idx] = o;
}

extern "C" void kernel_launch(void* const* d_in, const int* in_sizes, int n_in,
                              void* d_out, int out_size, void* d_ws, size_t ws_size,
                              hipStream_t stream) {
    (void)in_sizes; (void)n_in; (void)out_size; (void)ws_size;
    const float* x_data = (const float*)d_in[0];
    const float* x_faet = (const float*)d_in[1];
    const float* ew1 = (const float*)d_in[2];  const float* eb1 = (const float*)d_in[3];
    const float* ew2 = (const float*)d_in[4];  const float* eb2 = (const float*)d_in[5];
    const float* ew3 = (const float*)d_in[6];  const float* eb3 = (const float*)d_in[7];
    const float* tw1 = (const float*)d_in[8];  const float* tb1 = (const float*)d_in[9];
    const float* tw2 = (const float*)d_in[10]; const float* tb2 = (const float*)d_in[11];
    const float* tw3 = (const float*)d_in[12]; const float* tb3 = (const float*)d_in[13];
    float* out = (float*)d_out;

    // workspace layout (floats); h1 reused as Wk, h2 reused as acc. total ~34.2 MB
    float* ws    = (float*)d_ws;
    float* h1    = ws;                    // 3,276,800
    float* h2    = h1 + 3276800;          // 3,276,800
    float* xe    = h2 + 3276800;          //   409,600
    float* ltm   = xe + 409600;           //    51,200
    float* ye    = ltm + 51200;           // 1,537,600
    float* yn    = ye + 1537600;          //     2,048
    float* tempv = yn + 2048;             //     2,048
    float* wkbuf = h1;
    float* acc   = h2;

    dim3 cb(16, 16);
    // embedding CNN
    conv3x3_k<CFEAT, 8, true ><<<dim3(10, 10, BN * 8), cb, 0, stream>>>(x_faet, ew1, eb1, h1, 8);
    conv3x3_k<64,    8, true ><<<dim3(10, 10, BN * 8), cb, 0, stream>>>(h1,     ew2, eb2, h2, 8);
    conv3x3_k<64,    8, false><<<dim3(10, 10, BN * 1), cb, 0, stream>>>(h2,     ew3, eb3, xe, 1);
    // temperature CNN
    conv3x3_k<CFEAT, 8, true ><<<dim3(10, 10, BN * 8), cb, 0, stream>>>(x_faet, tw1, tb1, h1, 8);
    conv3x3_k<64,    8, true ><<<dim3(10, 10, BN * 8), cb, 0, stream>>>(h1,     tw2, tb2, h2, 8);
    conv3x3_k<64,    1, false><<<dim3(10, 10, BN * 1), cb, 0, stream>>>(h2,     tw3, tb3, ltm, 1);

    im2patch_k<<<BN * NSITE, 256, 0, stream>>>(xe, ltm, ye, yn, tempv);
    dist_softmax_k<<<BN * NSITE, 256, 0, stream>>>(ye, yn, tempv, wkbuf);

    hipMemsetAsync(acc, 0, (size_t)3276800 * sizeof(float), stream);
    for (int c1 = 0; c1 < 2; c1++)
        for (int c2 = 0; c2 < 2; c2++) {
            int n1c = (c1 == 0) ? 16 : 15, n2c = (c2 == 0) ? 16 : 15;
            agg_k<<<BN * n1c * n2c, 256, 0, stream>>>(wkbuf, x_data, acc, c1, c2, n1c, n2c);
        }
    finalize_k<<<(BN * 64 * HH * WW) / 256, 256, 0, stream>>>(acc, x_data, out);
}

// Round 2
// 826.201 us; speedup vs baseline: 1.4334x; 1.4334x over previous
//
#include <hip/hip_runtime.h>
#include <math.h>

#define BN 2
#define HH 160
#define WW 160
#define CDATA 8
#define CFEAT 8
#define CEMB 8
#define PS 10
#define STR 5
#define N1 31
#define N2 31
#define NSITE (N1*N2)
#define SWIN 15
#define NOFF 225
#define KK 7
#define EDIM 800
#define CHUNK 256   // gram k-chunk (floats)

// ---------- block reductions (256 threads = 4 waves) ----------
__device__ __forceinline__ float block_sum(float v, float* sred) {
    #pragma unroll
    for (int o = 32; o; o >>= 1) v += __shfl_xor(v, o);
    __syncthreads();
    if ((threadIdx.x & 63) == 0) sred[threadIdx.x >> 6] = v;
    __syncthreads();
    return sred[0] + sred[1] + sred[2] + sred[3];
}

__device__ __forceinline__ float block_max(float v, float* sred) {
    #pragma unroll
    for (int o = 32; o; o >>= 1) v = fmaxf(v, __shfl_xor(v, o));
    __syncthreads();
    if ((threadIdx.x & 63) == 0) sred[threadIdx.x >> 6] = v;
    __syncthreads();
    return fmaxf(fmaxf(sred[0], sred[1]), fmaxf(sred[2], sred[3]));
}

// ---------- 3x3 SAME conv, NCHW / OIHW, stride 1 ----------
template<int CIN, int NCO, bool RELU>
__global__ __launch_bounds__(256) void conv3x3_k(const float* __restrict__ in,
                                                 const float* __restrict__ wgt,
                                                 const float* __restrict__ bias,
                                                 float* __restrict__ out, int ngroups) {
    int x = blockIdx.x * 16 + threadIdx.x;
    int y = blockIdx.y * 16 + threadIdx.y;
    int bz = blockIdx.z;
    int b = bz / ngroups, g = bz % ngroups;
    int co0 = g * NCO;
    float acc[NCO];
    #pragma unroll
    for (int u = 0; u < NCO; u++) acc[u] = bias[co0 + u];
    const float* inb = in + (size_t)b * CIN * HH * WW;
    for (int c = 0; c < CIN; c++) {
        const float* inc = inb + (size_t)c * HH * WW;
        #pragma unroll
        for (int dy = 0; dy < 3; dy++) {
            int yy = y + dy - 1;
            bool yok = (yy >= 0 && yy < HH);
            #pragma unroll
            for (int dx = 0; dx < 3; dx++) {
                int xx = x + dx - 1;
                float v = (yok && xx >= 0 && xx < WW) ? inc[yy * WW + xx] : 0.f;
                #pragma unroll
                for (int u = 0; u < NCO; u++)
                    acc[u] = fmaf(v, wgt[((co0 + u) * CIN + c) * 9 + dy * 3 + dx], acc[u]);
            }
        }
    }
    float* outb = out + ((size_t)(b * (ngroups * NCO) + co0)) * HH * WW + y * WW + x;
    #pragma unroll
    for (int u = 0; u < NCO; u++) {
        float v = acc[u];
        if (RELU) v = fmaxf(v, 0.f);
        outb[(size_t)u * HH * WW] = v;
    }
}

// ---------- im2patch of xe -> ye rows, yn = ||ye||^2, tempv ----------
__global__ __launch_bounds__(256) void im2patch_k(const float* __restrict__ xe,
                                                  const float* __restrict__ ltm,
                                                  float* __restrict__ ye,
                                                  float* __restrict__ yn,
                                                  float* __restrict__ tempv) {
    __shared__ float sred[4];
    int site = blockIdx.x;
    int b = site / NSITE; int ij = site % NSITE;
    int i1 = ij / N2, i2 = ij % N2;
    int t = threadIdx.x;
    const float* xeb = xe + (size_t)b * CEMB * HH * WW;
    float* yrow = ye + (size_t)site * EDIM;
    float ssq = 0.f;
    for (int e = t; e < EDIM; e += 256) {
        int c = e / 100; int rr = (e / 10) % 10; int q = e % 10;
        float v = xeb[(size_t)c * HH * WW + (i1 * STR + rr) * WW + (i2 * STR + q)];
        yrow[e] = v; ssq += v * v;
    }
    float tot = block_sum(ssq, sred);
    if (t == 0) yn[site] = tot;
    float sl = 0.f;
    if (t < 100) {
        int rr = t / 10, q = t % 10;
        sl = ltm[(size_t)b * HH * WW + (i1 * STR + rr) * WW + (i2 * STR + q)];
    }
    float slt = block_sum(sl, sred);
    if (t == 0) tempv[site] = expf(slt * (1.f / 100.f));
}

// ---------- gram: per (b, i1, dj) compute 31x31 dot block ----------
// dots[(b*31+i1)*15+dj][i2*31+j2] = <ye[b,i1,i2], ye[b,j1=b1+dj,j2]>
__global__ __launch_bounds__(128) void gram_k(const float* __restrict__ ye,
                                              float* __restrict__ dots) {
    __shared__ float As[32 * CHUNK];   // 32 KB
    __shared__ float Bs[32 * CHUNK];   // 32 KB
    int blk = blockIdx.x;              // b*465 + i1*15 + dj
    int b = blk / 465; int r = blk % 465;
    int i1 = r / 15, dj = r % 15;
    int b1 = min(max(i1 - 7, 0), 16);
    int j1 = b1 + dj;
    const float* Arow = ye + (size_t)(b * N1 + i1) * N2 * EDIM;
    const float* Brow = ye + (size_t)(b * N1 + j1) * N2 * EDIM;
    int t = threadIdx.x;
    int tx = t & 15, ty = t >> 4;      // ty in [0,8)
    float acc[4][2];
    #pragma unroll
    for (int i = 0; i < 4; i++) { acc[i][0] = 0.f; acc[i][1] = 0.f; }
    for (int kc = 0; kc < EDIM; kc += CHUNK) {
        int len = min(CHUNK, EDIM - kc);
        int nq = len >> 2;
        for (int idx = t; idx < 31 * nq; idx += 128) {
            int row = idx / nq, gq = idx % nq;
            int sw = 4 * (gq ^ (row & 7));
            float4 va = *(const float4*)(Arow + (size_t)row * EDIM + kc + 4 * gq);
            *(float4*)(As + row * CHUNK + sw) = va;
            float4 vb = *(const float4*)(Brow + (size_t)row * EDIM + kc + 4 * gq);
            *(float4*)(Bs + row * CHUNK + sw) = vb;
        }
        __syncthreads();
        int swa = ty & 7, swb = tx & 7;
        for (int g = 0; g < nq; ++g) {
            float4 a0 = *(const float4*)(As + (ty     ) * CHUNK + 4 * (g ^ swa));
            float4 a1 = *(const float4*)(As + (ty + 8 ) * CHUNK + 4 * (g ^ swa));
            float4 a2 = *(const float4*)(As + (ty + 16) * CHUNK + 4 * (g ^ swa));
            float4 a3 = *(const float4*)(As + (ty + 24) * CHUNK + 4 * (g ^ swa));
            float4 b0 = *(const float4*)(Bs + (tx     ) * CHUNK + 4 * (g ^ swb));
            float4 b1 = *(const float4*)(Bs + (tx + 16) * CHUNK + 4 * (g ^ swb));
            float4 av[4] = {a0, a1, a2, a3};
            float4 bv[2] = {b0, b1};
            #pragma unroll
            for (int i = 0; i < 4; i++)
                #pragma unroll
                for (int j = 0; j < 2; j++) {
                    acc[i][j] = fmaf(av[i].x, bv[j].x, acc[i][j]);
                    acc[i][j] = fmaf(av[i].y, bv[j].y, acc[i][j]);
                    acc[i][j] = fmaf(av[i].z, bv[j].z, acc[i][j]);
                    acc[i][j] = fmaf(av[i].w, bv[j].w, acc[i][j]);
                }
        }
        __syncthreads();
    }
    float* dst = dots + (size_t)blk * (N2 * N2);
    #pragma unroll
    for (int i = 0; i < 4; i++) {
        int row = ty + 8 * i;
        if (row < 31) {
            if (tx < 31)      dst[row * 31 + tx]      = acc[i][0];
            if (tx + 16 < 31) dst[row * 31 + tx + 16] = acc[i][1];
        }
    }
}

// ---------- per-site K=7 iterated softmax from precomputed dots ----------
__global__ __launch_bounds__(256) void softmax_k(const float* __restrict__ dots,
                                                 const float* __restrict__ yn,
                                                 const float* __restrict__ tempv,
                                                 float* __restrict__ wkout) {
    __shared__ float sred[4];
    int site = blockIdx.x;
    int b = site / NSITE; int ij = site % NSITE;
    int i1 = ij / N2, i2 = ij % N2;
    int t = threadIdx.x;
    int b1 = min(max(i1 - 7, 0), 16);
    int b2 = min(max(i2 - 7, 0), 16);
    float logit = -1e9f;
    if (t < NOFF) {
        int dj = t / SWIN, dc = t % SWIN;
        int j1 = b1 + dj, j2 = b2 + dc;
        float dot = dots[((size_t)(b * N1 + i1) * SWIN + dj) * (N2 * N2) + i2 * 31 + j2];
        float xn = yn[(b * N1 + j1) * N2 + j2];
        float d = yn[site] + xn - 2.f * dot;
        logit = -d / tempv[site];
        if (j1 == i1 && j2 == i2) logit = -1e9f;
    }
    float* wkr = wkout + (size_t)site * (KK * NOFF);
    for (int k = 0; k < KK; k++) {
        float m = block_max(logit, sred);
        float ex = expf(logit - m);
        float s = block_sum(ex, sred);
        float wgt = ex / s;
        if (t < NOFF) wkr[k * NOFF + t] = wgt;
        logit += log1pf(-fminf(wgt, 1.f - 1e-6f));
    }
}

// ---------- aggregation: block = (color site, channel pair), LDS window ----------
__global__ __launch_bounds__(256) void agg_k(const float* __restrict__ wk,
                                             const float* __restrict__ xd,
                                             float* __restrict__ acc,
                                             int c1, int c2, int n1c, int n2c) {
    __shared__ float win[2 * 80 * 80];   // 51.2 KB: 2 channels x 80x80 window
    __shared__ float swk[NOFF * 8];      // [off][k] padded to 8 -> float4 pairs
    int t = threadIdx.x;
    int blk = blockIdx.x;
    int cp = blk & 3; int r = blk >> 2;
    int b = r / (n1c * n2c); int rr = r % (n1c * n2c);
    int i1 = c1 + 2 * (rr / n2c), i2 = c2 + 2 * (rr % n2c);
    int site = (b * N1 + i1) * N2 + i2;
    const float* wkr = wk + (size_t)site * (KK * NOFF);
    for (int l = t; l < KK * NOFF; l += 256) {
        int k = l / NOFF, off = l % NOFF;
        swk[off * 8 + k] = wkr[l];
    }
    int pb1 = min(max(i1 - 7, 0), 16) * STR;   // window base pixel row
    int pb2 = min(max(i2 - 7, 0), 16) * STR;
    for (int l = t; l < 12800; l += 256) {
        int c = l / 6400, rem = l % 6400;
        int wr = rem / 80, wc = rem % 80;
        win[l] = xd[((size_t)(b * CDATA + 2 * cp + c) * HH + pb1 + wr) * WW + pb2 + wc];
    }
    __syncthreads();
    if (t >= 200) return;
    int cd2 = t / 100, pix = t % 100;
    int pi = pix / 10, pj = pix % 10;
    float a0 = 0.f, a1 = 0.f, a2 = 0.f, a3 = 0.f, a4 = 0.f, a5 = 0.f, a6 = 0.f;
    const float* w0 = win + cd2 * 6400 + pi * 80 + pj;
    #pragma unroll 3
    for (int s1 = 0; s1 < SWIN; s1++) {
        const float* wrow = w0 + s1 * 400;
        const float* krow = swk + s1 * SWIN * 8;
        #pragma unroll 5
        for (int s2 = 0; s2 < SWIN; s2++) {
            float v = wrow[s2 * 5];
            float4 wa = *(const float4*)(krow + s2 * 8);
            float4 wb = *(const float4*)(krow + s2 * 8 + 4);
            a0 = fmaf(wa.x, v, a0); a1 = fmaf(wa.y, v, a1);
            a2 = fmaf(wa.z, v, a2); a3 = fmaf(wa.w, v, a3);
            a4 = fmaf(wb.x, v, a4); a5 = fmaf(wb.y, v, a5);
            a6 = fmaf(wb.z, v, a6);
        }
    }
    int h = i1 * STR + pi, w_ = i2 * STR + pj;
    int cd = 2 * cp + cd2;
    float av[KK] = {a0, a1, a2, a3, a4, a5, a6};
    #pragma unroll
    for (int k = 0; k < KK; k++) {
        size_t idx = ((size_t)(b * 64 + (k + 1) * CDATA + cd) * HH + h) * WW + w_;
        acc[idx] += av[k];     // color partition -> no races
    }
}

// ---------- finalize: out = [x_data ; acc/cnt - x_data] ----------
__global__ __launch_bounds__(256) void finalize_k(const float* __restrict__ acc,
                                                  const float* __restrict__ xd,
                                                  float* __restrict__ out) {
    int idx = blockIdx.x * 256 + threadIdx.x;
    if (idx >= BN * 64 * HH * WW) return;
    int w_ = idx % WW; int h = (idx / WW) % HH;
    int ch = (idx / (HH * WW)) % 64; int b = idx / (64 * HH * WW);
    int cd = ch & 7; int kk = ch >> 3;
    float xv = xd[((size_t)(b * CDATA + cd) * HH + h) * WW + w_];
    float o;
    if (kk == 0) {
        o = xv;
    } else {
        int lo1 = max(0, (h - 5) / 5),  hi1 = min(30, h / 5);
        int lo2 = max(0, (w_ - 5) / 5), hi2 = min(30, w_ / 5);
        float cnt = (float)((hi1 - lo1 + 1) * (hi2 - lo2 + 1));
        o = acc[idx] / cnt - xv;
    }
    out[idx] = o;
}

extern "C" void kernel_launch(void* const* d_in, const int* in_sizes, int n_in,
                              void* d_out, int out_size, void* d_ws, size_t ws_size,
                              hipStream_t stream) {
    (void)in_sizes; (void)n_in; (void)out_size; (void)ws_size;
    const float* x_data = (const float*)d_in[0];
    const float* x_faet = (const float*)d_in[1];
    const float* ew1 = (const float*)d_in[2];  const float* eb1 = (const float*)d_in[3];
    const float* ew2 = (const float*)d_in[4];  const float* eb2 = (const float*)d_in[5];
    const float* ew3 = (const float*)d_in[6];  const float* eb3 = (const float*)d_in[7];
    const float* tw1 = (const float*)d_in[8];  const float* tb1 = (const float*)d_in[9];
    const float* tw2 = (const float*)d_in[10]; const float* tb2 = (const float*)d_in[11];
    const float* tw3 = (const float*)d_in[12]; const float* tb3 = (const float*)d_in[13];
    float* out = (float*)d_out;

    // workspace layout (floats); h1 reused as Wk, h2 reused as acc. ~38 MB
    float* ws    = (float*)d_ws;
    float* h1    = ws;                    // 3,276,800
    float* h2    = h1 + 3276800;          // 3,276,800
    float* xe    = h2 + 3276800;          //   409,600
    float* ltm   = xe + 409600;           //    51,200
    float* ye    = ltm + 51200;           // 1,537,600
    float* yn    = ye + 1537600;          //     2,048
    float* tempv = yn + 2048;             //     2,048
    float* dots  = tempv + 2048;          //   893,730 (930 * 961)
    float* wkbuf = h1;
    float* acc   = h2;

    dim3 cb(16, 16);
    conv3x3_k<CFEAT, 8, true ><<<dim3(10, 10, BN * 8), cb, 0, stream>>>(x_faet, ew1, eb1, h1, 8);
    conv3x3_k<64,    8, true ><<<dim3(10, 10, BN * 8), cb, 0, stream>>>(h1,     ew2, eb2, h2, 8);
    conv3x3_k<64,    8, false><<<dim3(10, 10, BN * 1), cb, 0, stream>>>(h2,     ew3, eb3, xe, 1);
    conv3x3_k<CFEAT, 8, true ><<<dim3(10, 10, BN * 8), cb, 0, stream>>>(x_faet, tw1, tb1, h1, 8);
    conv3x3_k<64,    8, true ><<<dim3(10, 10, BN * 8), cb, 0, stream>>>(h1,     tw2, tb2, h2, 8);
    conv3x3_k<64,    1, false><<<dim3(10, 10, BN * 1), cb, 0, stream>>>(h2,     tw3, tb3, ltm, 1);

    im2patch_k<<<BN * NSITE, 256, 0, stream>>>(xe, ltm, ye, yn, tempv);
    gram_k<<<BN * N1 * SWIN, 128, 0, stream>>>(ye, dots);
    softmax_k<<<BN * NSITE, 256, 0, stream>>>(dots, yn, tempv, wkbuf);

    hipMemsetAsync(acc, 0, (size_t)3276800 * sizeof(float), stream);
    for (int c1 = 0; c1 < 2; c1++)
        for (int c2 = 0; c2 < 2; c2++) {
            int n1c = (c1 == 0) ? 16 : 15, n2c = (c2 == 0) ? 16 : 15;
            agg_k<<<BN * n1c * n2c * 4, 256, 0, stream>>>(wkbuf, x_data, acc, c1, c2, n1c, n2c);
        }
    finalize_k<<<(BN * 64 * HH * WW) / 256, 256, 0, stream>>>(acc, x_data, out);
}

// Round 3
// 520.203 us; speedup vs baseline: 2.2766x; 1.5882x over previous
//
#include <hip/hip_runtime.h>
#include <math.h>

#define BN 2
#define HH 160
#define WW 160
#define CDATA 8
#define PS 10
#define STR 5
#define N1 31
#define N2 31
#define NSITE (N1*N2)
#define SWIN 15
#define NOFF 225
#define KK 7
#define EDIM 800
#define CHUNK 256
#define NPIX 25600          // HH*WW
#define LP 40               // LDS pitch (ushorts): 32 k + 8 pad

typedef __attribute__((ext_vector_type(8))) short s8v;
typedef __attribute__((ext_vector_type(8))) unsigned short u8v;
typedef __attribute__((ext_vector_type(4))) float f4v;

__device__ __forceinline__ unsigned short f2bf(float f) {
    unsigned u = __float_as_uint(f);
    return (unsigned short)((u + 0x7FFFu + ((u >> 16) & 1u)) >> 16);
}
__device__ __forceinline__ float bf2f(unsigned short h) {
    return __uint_as_float(((unsigned)h) << 16);
}

// ---------- block reductions (256 threads = 4 waves) ----------
__device__ __forceinline__ float block_sum(float v, float* sred) {
    #pragma unroll
    for (int o = 32; o; o >>= 1) v += __shfl_xor(v, o);
    __syncthreads();
    if ((threadIdx.x & 63) == 0) sred[threadIdx.x >> 6] = v;
    __syncthreads();
    return sred[0] + sred[1] + sred[2] + sred[3];
}
__device__ __forceinline__ float block_max(float v, float* sred) {
    #pragma unroll
    for (int o = 32; o; o >>= 1) v = fmaxf(v, __shfl_xor(v, o));
    __syncthreads();
    if ((threadIdx.x & 63) == 0) sred[threadIdx.x >> 6] = v;
    __syncthreads();
    return fmaxf(fmaxf(sred[0], sred[1]), fmaxf(sred[2], sred[3]));
}

// ---------- prepack conv2 weights: [2][n=64][k=576], k = (dy*3+dx)*64 + c ----------
__global__ __launch_bounds__(256) void prepack_w2_k(const float* __restrict__ ew2,
                                                    const float* __restrict__ tw2,
                                                    unsigned short* __restrict__ wp) {
    int idx = blockIdx.x * 256 + threadIdx.x;
    if (idx >= 2 * 64 * 576) return;
    int which = idx / (64 * 576); int r = idx % (64 * 576);
    int n = r / 576, k = r % 576;
    int p = k / 64, c = k % 64;
    const float* w = which ? tw2 : ew2;
    wp[idx] = f2bf(w[(n * 64 + c) * 9 + p]);
}

// ---------- conv1 (e+t fused), fp32 math, writes bf16 NHWC h1 [b][pix][128] ----------
__global__ __launch_bounds__(256) void conv1_k(const float* __restrict__ xf,
                                               const float* __restrict__ ew1,
                                               const float* __restrict__ eb1,
                                               const float* __restrict__ tw1,
                                               const float* __restrict__ tb1,
                                               unsigned short* __restrict__ h1) {
    int x = blockIdx.x * 16 + threadIdx.x;
    int y = blockIdx.y * 16 + threadIdx.y;
    int z = blockIdx.z; int b = z >> 3, g = z & 7;
    const float* wgt  = (g < 4) ? ew1 : tw1;
    const float* bias = (g < 4) ? eb1 : tb1;
    int co0 = (g & 3) * 16;
    float acc[16];
    #pragma unroll
    for (int u = 0; u < 16; u++) acc[u] = bias[co0 + u];
    const float* inb = xf + (size_t)b * 8 * NPIX;
    for (int c = 0; c < 8; ++c) {
        const float* inc = inb + c * NPIX;
        #pragma unroll
        for (int dy = 0; dy < 3; ++dy) {
            int yy = y + dy - 1; bool yok = (yy >= 0 && yy < HH);
            #pragma unroll
            for (int dx = 0; dx < 3; ++dx) {
                int xx = x + dx - 1;
                float v = (yok && xx >= 0 && xx < WW) ? inc[yy * WW + xx] : 0.f;
                #pragma unroll
                for (int u = 0; u < 16; u++)
                    acc[u] = fmaf(v, wgt[((co0 + u) * 8 + c) * 9 + dy * 3 + dx], acc[u]);
            }
        }
    }
    u8v o0, o1;
    #pragma unroll
    for (int u = 0; u < 8; u++) o0[u] = f2bf(fmaxf(acc[u], 0.f));
    #pragma unroll
    for (int u = 0; u < 8; u++) o1[u] = f2bf(fmaxf(acc[8 + u], 0.f));
    unsigned short* dst = h1 + ((size_t)b * NPIX + y * WW + x) * 128 + g * 16;
    *(u8v*)dst = o0;
    *(u8v*)(dst + 8) = o1;
}

// ---------- conv2: bf16 MFMA implicit GEMM. D[n=64 outch][m=64 pixels] per block ----------
__global__ __launch_bounds__(256) void conv2_mfma_k(const unsigned short* __restrict__ h1,
                                                    const unsigned short* __restrict__ wp,
                                                    const float* __restrict__ eb2,
                                                    const float* __restrict__ tb2,
                                                    unsigned short* __restrict__ h2) {
    __shared__ unsigned short Al[64 * LP];   // weights [n][k32]
    __shared__ unsigned short Bl[64 * LP];   // pixels  [m][k32]
    const int t = threadIdx.x;
    const int which = blockIdx.y;
    const int m0 = blockIdx.x * 64;
    const int wv = t >> 6, lane = t & 63;
    const int n0w = (wv >> 1) * 32, m0w = (wv & 1) * 32;
    f4v a00 = {0.f,0.f,0.f,0.f}, a01 = a00, a10 = a00, a11 = a00;
    const unsigned short* wb = wp + (size_t)which * 64 * 576;
    const int sm = t >> 2, sq = (t & 3) * 8;
    const int mp = m0 + sm;
    const int b = mp / NPIX, rp = mp % NPIX;
    const int py = rp / WW, px = rp % WW;
    for (int step = 0; step < 18; ++step) {
        const int p = step >> 1, ch = (step & 1) * 32;
        const int dy = p / 3 - 1, dx = p % 3 - 1;
        s8v av = *(const s8v*)(wb + sm * 576 + p * 64 + ch + sq);
        s8v bv; 
        #pragma unroll
        for (int j = 0; j < 8; j++) bv[j] = 0;
        int yy = py + dy, xx = px + dx;
        if (yy >= 0 && yy < HH && xx >= 0 && xx < WW)
            bv = *(const s8v*)((const short*)h1 + ((size_t)b * NPIX + yy * WW + xx) * 128 + which * 64 + ch + sq);
        __syncthreads();
        *(s8v*)((short*)Al + sm * LP + sq) = av;
        *(s8v*)((short*)Bl + sm * LP + sq) = bv;
        __syncthreads();
        s8v af0 = *(const s8v*)((const short*)Al + (n0w      + (lane & 15)) * LP + (lane >> 4) * 8);
        s8v af1 = *(const s8v*)((const short*)Al + (n0w + 16 + (lane & 15)) * LP + (lane >> 4) * 8);
        s8v bf0 = *(const s8v*)((const short*)Bl + (m0w      + (lane & 15)) * LP + (lane >> 4) * 8);
        s8v bf1 = *(const s8v*)((const short*)Bl + (m0w + 16 + (lane & 15)) * LP + (lane >> 4) * 8);
        a00 = __builtin_amdgcn_mfma_f32_16x16x32_bf16(af0, bf0, a00, 0, 0, 0);
        a01 = __builtin_amdgcn_mfma_f32_16x16x32_bf16(af0, bf1, a01, 0, 0, 0);
        a10 = __builtin_amdgcn_mfma_f32_16x16x32_bf16(af1, bf0, a10, 0, 0, 0);
        a11 = __builtin_amdgcn_mfma_f32_16x16x32_bf16(af1, bf1, a11, 0, 0, 0);
    }
    const float* bias = which ? tb2 : eb2;
    #pragma unroll
    for (int fj = 0; fj < 2; ++fj) {
        int nb = n0w + fj * 16 + (lane >> 4) * 4;
        f4v bv4 = *(const f4v*)(bias + nb);
        #pragma unroll
        for (int fi = 0; fi < 2; ++fi) {
            f4v ac = fj ? (fi ? a11 : a10) : (fi ? a01 : a00);
            int mm = m0 + m0w + fi * 16 + (lane & 15);
            ushort4 o;
            o.x = f2bf(fmaxf(ac[0] + bv4[0], 0.f));
            o.y = f2bf(fmaxf(ac[1] + bv4[1], 0.f));
            o.z = f2bf(fmaxf(ac[2] + bv4[2], 0.f));
            o.w = f2bf(fmaxf(ac[3] + bv4[3], 0.f));
            *(ushort4*)(h2 + ((size_t)which * 51200 + mm) * 64 + nb) = o;
        }
    }
}

// ---------- conv3 (e+t fused): bf16 NHWC in, fp32 math, xe NHWC [b][pix][8], ltm plane ----------
__global__ __launch_bounds__(256) void conv3_k(const unsigned short* __restrict__ h2,
                                               const float* __restrict__ ew3,
                                               const float* __restrict__ eb3,
                                               const float* __restrict__ tw3,
                                               const float* __restrict__ tb3,
                                               float* __restrict__ xe,
                                               float* __restrict__ ltm) {
    int x = blockIdx.x * 16 + threadIdx.x;
    int y = blockIdx.y * 16 + threadIdx.y;
    int z = blockIdx.z; int b = z >> 1, which = z & 1;
    const unsigned short* h2b = h2 + ((size_t)which * 51200 + b * NPIX) * 64;
    if (which == 0) {
        float acc[8];
        #pragma unroll
        for (int u = 0; u < 8; u++) acc[u] = eb3[u];
        #pragma unroll
        for (int pos = 0; pos < 9; ++pos) {
            int yy = y + pos / 3 - 1, xx = x + pos % 3 - 1;
            if (yy < 0 || yy >= HH || xx < 0 || xx >= WW) continue;
            const unsigned short* row = h2b + ((size_t)yy * WW + xx) * 64;
            for (int cq = 0; cq < 8; ++cq) {
                u8v v = *(const u8v*)(row + cq * 8);
                #pragma unroll
                for (int j = 0; j < 8; ++j) {
                    float f = bf2f(v[j]);
                    int c = cq * 8 + j;
                    #pragma unroll
                    for (int u = 0; u < 8; u++)
                        acc[u] = fmaf(f, ew3[(u * 64 + c) * 9 + pos], acc[u]);
                }
            }
        }
        float* dst = xe + ((size_t)b * NPIX + y * WW + x) * 8;
        #pragma unroll
        for (int u = 0; u < 8; u++) dst[u] = acc[u];
    } else {
        float acc = tb3[0];
        #pragma unroll
        for (int pos = 0; pos < 9; ++pos) {
            int yy = y + pos / 3 - 1, xx = x + pos % 3 - 1;
            if (yy < 0 || yy >= HH || xx < 0 || xx >= WW) continue;
            const unsigned short* row = h2b + ((size_t)yy * WW + xx) * 64;
            for (int cq = 0; cq < 8; ++cq) {
                u8v v = *(const u8v*)(row + cq * 8);
                #pragma unroll
                for (int j = 0; j < 8; ++j)
                    acc = fmaf(bf2f(v[j]), tw3[(cq * 8 + j) * 9 + pos], acc);
            }
        }
        ltm[b * NPIX + y * WW + x] = acc;
    }
}

// ---------- im2patch (NHWC xe): ye[site][e], e = (rr*10+q)*8 + c ----------
__global__ __launch_bounds__(256) void im2patch_k(const float* __restrict__ xe,
                                                  const float* __restrict__ ltm,
                                                  float* __restrict__ ye,
                                                  float* __restrict__ yn,
                                                  float* __restrict__ tempv) {
    __shared__ float sred[4];
    int site = blockIdx.x;
    int b = site / NSITE; int ij = site % NSITE;
    int i1 = ij / N2, i2 = ij % N2;
    int t = threadIdx.x;
    const float* xeb = xe + (size_t)b * NPIX * 8;
    float* yrow = ye + (size_t)site * EDIM;
    float ssq = 0.f;
    for (int e = t; e < EDIM; e += 256) {
        int rr = e / 80, rem = e % 80;
        float v = xeb[((size_t)(i1 * STR + rr) * WW + i2 * STR) * 8 + rem];
        yrow[e] = v; ssq += v * v;
    }
    float tot = block_sum(ssq, sred);
    if (t == 0) yn[site] = tot;
    float sl = 0.f;
    if (t < 100) {
        int rr = t / 10, q = t % 10;
        sl = ltm[(size_t)b * NPIX + (i1 * STR + rr) * WW + (i2 * STR + q)];
    }
    float slt = block_sum(sl, sred);
    if (t == 0) tempv[site] = expf(slt * (1.f / 100.f));
}

// ---------- gram: per (b, i1, dj) compute 31x31 dot block ----------
__global__ __launch_bounds__(128) void gram_k(const float* __restrict__ ye,
                                              float* __restrict__ dots) {
    __shared__ float As[32 * CHUNK];
    __shared__ float Bs[32 * CHUNK];
    int blk = blockIdx.x;
    int b = blk / 465; int r = blk % 465;
    int i1 = r / 15, dj = r % 15;
    int b1 = min(max(i1 - 7, 0), 16);
    int j1 = b1 + dj;
    const float* Arow = ye + (size_t)(b * N1 + i1) * N2 * EDIM;
    const float* Brow = ye + (size_t)(b * N1 + j1) * N2 * EDIM;
    int t = threadIdx.x;
    int tx = t & 15, ty = t >> 4;
    float acc[4][2];
    #pragma unroll
    for (int i = 0; i < 4; i++) { acc[i][0] = 0.f; acc[i][1] = 0.f; }
    for (int kc = 0; kc < EDIM; kc += CHUNK) {
        int len = min(CHUNK, EDIM - kc);
        int nq = len >> 2;
        for (int idx = t; idx < 31 * nq; idx += 128) {
            int row = idx / nq, gq = idx % nq;
            int sw = 4 * (gq ^ (row & 7));
            float4 va = *(const float4*)(Arow + (size_t)row * EDIM + kc + 4 * gq);
            *(float4*)(As + row * CHUNK + sw) = va;
            float4 vb = *(const float4*)(Brow + (size_t)row * EDIM + kc + 4 * gq);
            *(float4*)(Bs + row * CHUNK + sw) = vb;
        }
        __syncthreads();
        int swa = ty & 7, swb = tx & 7;
        for (int g = 0; g < nq; ++g) {
            float4 a0 = *(const float4*)(As + (ty     ) * CHUNK + 4 * (g ^ swa));
            float4 a1 = *(const float4*)(As + (ty + 8 ) * CHUNK + 4 * (g ^ swa));
            float4 a2 = *(const float4*)(As + (ty + 16) * CHUNK + 4 * (g ^ swa));
            float4 a3 = *(const float4*)(As + (ty + 24) * CHUNK + 4 * (g ^ swa));
            float4 b0 = *(const float4*)(Bs + (tx     ) * CHUNK + 4 * (g ^ swb));
            float4 b1 = *(const float4*)(Bs + (tx + 16) * CHUNK + 4 * (g ^ swb));
            float4 av[4] = {a0, a1, a2, a3};
            float4 bv[2] = {b0, b1};
            #pragma unroll
            for (int i = 0; i < 4; i++)
                #pragma unroll
                for (int j = 0; j < 2; j++) {
                    acc[i][j] = fmaf(av[i].x, bv[j].x, acc[i][j]);
                    acc[i][j] = fmaf(av[i].y, bv[j].y, acc[i][j]);
                    acc[i][j] = fmaf(av[i].z, bv[j].z, acc[i][j]);
                    acc[i][j] = fmaf(av[i].w, bv[j].w, acc[i][j]);
                }
        }
        __syncthreads();
    }
    float* dst = dots + (size_t)blk * (N2 * N2);
    #pragma unroll
    for (int i = 0; i < 4; i++) {
        int row = ty + 8 * i;
        if (row < 31) {
            if (tx < 31)      dst[row * 31 + tx]      = acc[i][0];
            if (tx + 16 < 31) dst[row * 31 + tx + 16] = acc[i][1];
        }
    }
}

// ---------- per-site K=7 iterated softmax ----------
__global__ __launch_bounds__(256) void softmax_k(const float* __restrict__ dots,
                                                 const float* __restrict__ yn,
                                                 const float* __restrict__ tempv,
                                                 float* __restrict__ wkout) {
    __shared__ float sred[4];
    int site = blockIdx.x;
    int b = site / NSITE; int ij = site % NSITE;
    int i1 = ij / N2, i2 = ij % N2;
    int t = threadIdx.x;
    int b1 = min(max(i1 - 7, 0), 16);
    int b2 = min(max(i2 - 7, 0), 16);
    float logit = -1e9f;
    if (t < NOFF) {
        int dj = t / SWIN, dc = t % SWIN;
        int j1 = b1 + dj, j2 = b2 + dc;
        float dot = dots[((size_t)(b * N1 + i1) * SWIN + dj) * (N2 * N2) + i2 * 31 + j2];
        float xn = yn[(b * N1 + j1) * N2 + j2];
        float d = yn[site] + xn - 2.f * dot;
        logit = -d / tempv[site];
        if (j1 == i1 && j2 == i2) logit = -1e9f;
    }
    float* wkr = wkout + (size_t)site * (KK * NOFF);
    for (int k = 0; k < KK; k++) {
        float m = block_max(logit, sred);
        float ex = expf(logit - m);
        float s = block_sum(ex, sred);
        float wgt = ex / s;
        if (t < NOFF) wkr[k * NOFF + t] = wgt;
        logit += log1pf(-fminf(wgt, 1.f - 1e-6f));
    }
}

// ---------- aggregation (4-color, LDS window) ----------
__global__ __launch_bounds__(256) void agg_k(const float* __restrict__ wk,
                                             const float* __restrict__ xd,
                                             float* __restrict__ acc,
                                             int c1, int c2, int n1c, int n2c) {
    __shared__ float win[2 * 80 * 80];
    __shared__ float swk[NOFF * 8];
    int t = threadIdx.x;
    int blk = blockIdx.x;
    int cp = blk & 3; int r = blk >> 2;
    int b = r / (n1c * n2c); int rr = r % (n1c * n2c);
    int i1 = c1 + 2 * (rr / n2c), i2 = c2 + 2 * (rr % n2c);
    int site = (b * N1 + i1) * N2 + i2;
    const float* wkr = wk + (size_t)site * (KK * NOFF);
    for (int l = t; l < KK * NOFF; l += 256) {
        int k = l / NOFF, off = l % NOFF;
        swk[off * 8 + k] = wkr[l];
    }
    int pb1 = min(max(i1 - 7, 0), 16) * STR;
    int pb2 = min(max(i2 - 7, 0), 16) * STR;
    for (int l = t; l < 12800; l += 256) {
        int c = l / 6400, rem = l % 6400;
        int wr = rem / 80, wc = rem % 80;
        win[l] = xd[((size_t)(b * CDATA + 2 * cp + c) * HH + pb1 + wr) * WW + pb2 + wc];
    }
    __syncthreads();
    if (t >= 200) return;
    int cd2 = t / 100, pix = t % 100;
    int pi = pix / 10, pj = pix % 10;
    float a0 = 0.f, a1 = 0.f, a2 = 0.f, a3 = 0.f, a4 = 0.f, a5 = 0.f, a6 = 0.f;
    const float* w0 = win + cd2 * 6400 + pi * 80 + pj;
    #pragma unroll 3
    for (int s1 = 0; s1 < SWIN; s1++) {
        const float* wrow = w0 + s1 * 400;
        const float* krow = swk + s1 * SWIN * 8;
        #pragma unroll 5
        for (int s2 = 0; s2 < SWIN; s2++) {
            float v = wrow[s2 * 5];
            float4 wa = *(const float4*)(krow + s2 * 8);
            float4 wb = *(const float4*)(krow + s2 * 8 + 4);
            a0 = fmaf(wa.x, v, a0); a1 = fmaf(wa.y, v, a1);
            a2 = fmaf(wa.z, v, a2); a3 = fmaf(wa.w, v, a3);
            a4 = fmaf(wb.x, v, a4); a5 = fmaf(wb.y, v, a5);
            a6 = fmaf(wb.z, v, a6);
        }
    }
    int h = i1 * STR + pi, w_ = i2 * STR + pj;
    int cd = 2 * cp + cd2;
    float av[KK] = {a0, a1, a2, a3, a4, a5, a6};
    #pragma unroll
    for (int k = 0; k < KK; k++) {
        size_t idx = ((size_t)(b * 64 + (k + 1) * CDATA + cd) * HH + h) * WW + w_;
        acc[idx] += av[k];
    }
}

// ---------- finalize ----------
__global__ __launch_bounds__(256) void finalize_k(const float* __restrict__ acc,
                                                  const float* __restrict__ xd,
                                                  float* __restrict__ out) {
    int idx = blockIdx.x * 256 + threadIdx.x;
    if (idx >= BN * 64 * HH * WW) return;
    int w_ = idx % WW; int h = (idx / WW) % HH;
    int ch = (idx / (HH * WW)) % 64; int b = idx / (64 * HH * WW);
    int cd = ch & 7; int kk = ch >> 3;
    float xv = xd[((size_t)(b * CDATA + cd) * HH + h) * WW + w_];
    float o;
    if (kk == 0) {
        o = xv;
    } else {
        int lo1 = max(0, (h - 5) / 5),  hi1 = min(30, h / 5);
        int lo2 = max(0, (w_ - 5) / 5), hi2 = min(30, w_ / 5);
        float cnt = (float)((hi1 - lo1 + 1) * (hi2 - lo2 + 1));
        o = acc[idx] / cnt - xv;
    }
    out[idx] = o;
}

extern "C" void kernel_launch(void* const* d_in, const int* in_sizes, int n_in,
                              void* d_out, int out_size, void* d_ws, size_t ws_size,
                              hipStream_t stream) {
    (void)in_sizes; (void)n_in; (void)out_size; (void)ws_size;
    const float* x_data = (const float*)d_in[0];
    const float* x_faet = (const float*)d_in[1];
    const float* ew1 = (const float*)d_in[2];  const float* eb1 = (const float*)d_in[3];
    const float* ew2 = (const float*)d_in[4];  const float* eb2 = (const float*)d_in[5];
    const float* ew3 = (const float*)d_in[6];  const float* eb3 = (const float*)d_in[7];
    const float* tw1 = (const float*)d_in[8];  const float* tb1 = (const float*)d_in[9];
    const float* tw2 = (const float*)d_in[10]; const float* tb2 = (const float*)d_in[11];
    const float* tw3 = (const float*)d_in[12]; const float* tb3 = (const float*)d_in[13];
    float* out = (float*)d_out;

    // byte-offset workspace layout (~34.4 MB peak, all offsets 256B aligned)
    char* base = (char*)d_ws;
    unsigned short* h1 = (unsigned short*)(base);              // 13,107,200 B
    unsigned short* h2 = (unsigned short*)(base + 13107200);   // 13,107,200 B
    unsigned short* wp = (unsigned short*)(base + 26214400);   //    147,456 B
    float* xe    = (float*)(base + 26361856);                  //  1,638,400 B
    float* ltm   = (float*)(base + 28000256);                  //    204,800 B
    float* ye    = (float*)(base + 28205056);                  //  6,150,400 B
    float* yn    = (float*)(base + 34355456);                  //      8,192 B
    float* tempv = (float*)(base + 34363648);                  //      8,192 B
    float* dots  = (float*)h2;      // alias: gram runs after conv3 consumed h2
    float* wkbuf = (float*)h1;      // alias: softmax runs after conv2 consumed h1
    float* acc   = (float*)h2;      // alias: memset after softmax consumed dots

    prepack_w2_k<<<(2 * 64 * 576 + 255) / 256, 256, 0, stream>>>(ew2, tw2, wp);
    conv1_k<<<dim3(10, 10, 16), dim3(16, 16), 0, stream>>>(x_faet, ew1, eb1, tw1, tb1, h1);
    conv2_mfma_k<<<dim3(800, 2), 256, 0, stream>>>(h1, wp, eb2, tb2, h2);
    conv3_k<<<dim3(10, 10, 4), dim3(16, 16), 0, stream>>>(h2, ew3, eb3, tw3, tb3, xe, ltm);

    im2patch_k<<<BN * NSITE, 256, 0, stream>>>(xe, ltm, ye, yn, tempv);
    gram_k<<<BN * N1 * SWIN, 128, 0, stream>>>(ye, dots);
    softmax_k<<<BN * NSITE, 256, 0, stream>>>(dots, yn, tempv, wkbuf);

    hipMemsetAsync(acc, 0, 13107200, stream);
    for (int c1 = 0; c1 < 2; c1++)
        for (int c2 = 0; c2 < 2; c2++) {
            int n1c = (c1 == 0) ? 16 : 15, n2c = (c2 == 0) ? 16 : 15;
            agg_k<<<BN * n1c * n2c * 4, 256, 0, stream>>>(wkbuf, x_data, acc, c1, c2, n1c, n2c);
        }
    finalize_k<<<(BN * 64 * HH * WW) / 256, 256, 0, stream>>>(acc, x_data, out);
}